// Round 4
// baseline (212.374 us; speedup 1.0000x reference)
//
#include <hip/hip_runtime.h>
#include <stdint.h>

// B=8, S=2048, F=512, D=128, C=1000. I/O fp32; internal bf16 MFMA, fp32 accum.
#define NB 8
#define SS 2048
#define FF 512
#define DD 128
#define CC 1000
#define KC 8              // KV split factor
#define CHUNK (SS / KC)   // 256

typedef __attribute__((ext_vector_type(8))) short bf16x8;
typedef __attribute__((ext_vector_type(4))) float f32x4;

__device__ __forceinline__ short f2bf(float f) {
    uint32_t u;
    __builtin_memcpy(&u, &f, 4);
    u = (u + 0x7fffu + ((u >> 16) & 1u)) >> 16;   // RNE
    return (short)u;
}

// async 16B global->LDS (m97 recipe): LDS dest is wave-uniform base + lane*16
__device__ __forceinline__ void async16(const void* g, void* l) {
    __builtin_amdgcn_global_load_lds(
        (const __attribute__((address_space(1))) uint32_t*)g,
        (__attribute__((address_space(3))) uint32_t*)l, 16, 0, 0);
}

// ---------------------------------------------------------------------------
// Kernel 0 (prep): cast x fp32->bf16 (blocks 0..4095) and transpose+cast the
// three projection weights [F][D]f32 -> [D][F]bf16 (blocks 4096..4863).
// ---------------------------------------------------------------------------
__global__ void prep(const float* __restrict__ x,
                     const float* __restrict__ Wq, const float* __restrict__ Wk,
                     const float* __restrict__ Wv,
                     short* __restrict__ xb, short* __restrict__ Wt)
{
    int bx = blockIdx.x;
    if (bx < 4096) {
        int id = bx * 256 + threadIdx.x;          // 1,048,576 threads x 8 elems
        const float4* src = (const float4*)x + id * 2;
        float4 a = src[0], b2 = src[1];
        bf16x8 o;
        o[0] = f2bf(a.x);  o[1] = f2bf(a.y);  o[2] = f2bf(a.z);  o[3] = f2bf(a.w);
        o[4] = f2bf(b2.x); o[5] = f2bf(b2.y); o[6] = f2bf(b2.z); o[7] = f2bf(b2.w);
        *(bf16x8*)(xb + id * 8) = o;
    } else {
        int id = (bx - 4096) * 256 + threadIdx.x; // 0..196607
        int w = id >> 16, rem = id & 65535;
        int n = rem >> 9, kx = rem & 511;         // n: D, kx: F
        const float* Wsrc = (w == 0) ? Wq : (w == 1) ? Wk : Wv;
        Wt[w * 65536 + n * 512 + kx] = f2bf(Wsrc[kx * 128 + n]);
    }
}

// ---------------------------------------------------------------------------
// Kernel 1: fused QKV projection. C[16384x128] = xb[16384x512] @ Wt^T + bias.
// grid = (128 m-tiles, 3 mats). 128x128 tile, BK=64, 4 waves each 64x64.
// m97-style: unpadded LDS + global_load_lds width 16.
// V stored transposed vt[b][d][s].
// ---------------------------------------------------------------------------
__global__ __launch_bounds__(256) void qkv_proj(
    const short* __restrict__ xb, const short* __restrict__ Wt,
    const float* __restrict__ bq, const float* __restrict__ bk, const float* __restrict__ bv,
    short* __restrict__ qo, short* __restrict__ ko, short* __restrict__ vto)
{
    __shared__ __align__(16) short As[128 * 64];   // [row][k] unpadded
    __shared__ __align__(16) short Bs[128 * 64];

    const int m0   = blockIdx.x * 128;
    const int mat  = blockIdx.y;
    const int tid  = threadIdx.x;
    const int wave = tid >> 6, lane = tid & 63;
    const int quad = lane >> 4, l16 = lane & 15;
    const int wr = wave >> 1, wc = wave & 1;

    const short* Wm = Wt + mat * 65536;

    f32x4 acc[4][4];
    for (int i = 0; i < 4; i++)
        for (int j = 0; j < 4; j++) acc[i][j] = (f32x4){0.f, 0.f, 0.f, 0.f};

    for (int kk = 0; kk < 512; kk += 64) {
        __syncthreads();                           // prior iter's LDS reads done
        for (int i = 0; i < 4; i++) {
            int ch = i * 256 + wave * 64 + lane;   // chunk id, 16B each
            int r_ = ch >> 3, c8 = ch & 7;
            async16(xb + (m0 + r_) * 512 + kk + c8 * 8, &As[(i * 256 + wave * 64) * 8]);
            async16(Wm + r_ * 512 + kk + c8 * 8,        &Bs[(i * 256 + wave * 64) * 8]);
        }
        __syncthreads();                           // drains vmcnt -> tiles visible

        for (int kc = 0; kc < 2; kc++) {
            bf16x8 af[4], bfr[4];
            for (int mt = 0; mt < 4; mt++)
                af[mt]  = *(const bf16x8*)&As[(wr * 64 + mt * 16 + l16) * 64 + kc * 32 + quad * 8];
            for (int nt = 0; nt < 4; nt++)
                bfr[nt] = *(const bf16x8*)&Bs[(wc * 64 + nt * 16 + l16) * 64 + kc * 32 + quad * 8];
            for (int mt = 0; mt < 4; mt++)
                for (int nt = 0; nt < 4; nt++)
                    acc[mt][nt] = __builtin_amdgcn_mfma_f32_16x16x32_bf16(
                        af[mt], bfr[nt], acc[mt][nt], 0, 0, 0);
        }
    }

    const float* bias = (mat == 0) ? bq : (mat == 1) ? bk : bv;
    for (int mt = 0; mt < 4; mt++) {
        int grow_base = m0 + wr * 64 + mt * 16 + quad * 4;   // C/D row = quad*4+reg
        for (int nt = 0; nt < 4; nt++) {
            int col = wc * 64 + nt * 16 + l16;               // C/D col = lane&15
            float bb = bias[col];
            for (int r = 0; r < 4; r++) {
                int grow = grow_base + r;
                short h = f2bf(acc[mt][nt][r] + bb);
                if (mat == 0)      qo[grow * 128 + col] = h;
                else if (mat == 1) ko[grow * 128 + col] = h;
                else {
                    int b_ = grow >> 11, si = grow & 2047;
                    vto[(b_ * 128 + col) * 2048 + si] = h;   // transposed V
                }
            }
        }
    }
}

// ---------------------------------------------------------------------------
// Kernel 2: split-KV flash attention, streaming softmax (fixed shift 10; the
// e^-10 cancels in O/l; logits bounded ~22 << 88). 128 q-rows per block:
// 4 waves x 2 m-frags of 16 rows -> K/V frags reused across m (LDS reads per
// MFMA halved). grid = (16 q-tiles, 8 batches, KC chunks) = 1024 blocks.
// ---------------------------------------------------------------------------
__global__ __launch_bounds__(256) void flash_partial(
    const short* __restrict__ q, const short* __restrict__ k,
    const short* __restrict__ vt, float* __restrict__ O_acc,
    float* __restrict__ l_buf)
{
    __shared__ __align__(16) short ks[32 * 128];      // [kv][d] unpadded
    __shared__ __align__(16) short vs[128 * 32];      // [d][kv] unpadded
    __shared__ __align__(16) short ps[4 * 32 * 40];   // per-wave P [32][40]

    const int b   = blockIdx.y;
    const int q0  = blockIdx.x * 128;
    const int c0  = blockIdx.z * CHUNK;
    const int tid  = threadIdx.x;
    const int wave = tid >> 6, lane = tid & 63;
    const int quad = lane >> 4, l16 = lane & 15;

    // persistent Q fragments for 2 m-tiles: A[m=lane&15][kchunk=quad*8+j]
    bf16x8 qf[2][4];
    for (int m = 0; m < 2; m++)
        for (int c = 0; c < 4; c++)
            qf[m][c] = *(const bf16x8*)(q + (b * 2048 + q0 + wave * 32 + m * 16 + l16) * 128
                                          + c * 32 + quad * 8);

    f32x4 O[2][8];
    for (int m = 0; m < 2; m++)
        for (int t = 0; t < 8; t++) O[m][t] = (f32x4){0.f, 0.f, 0.f, 0.f};
    float l_[2][4] = {{0.f,0.f,0.f,0.f},{0.f,0.f,0.f,0.f}};

    short* psw = ps + wave * (32 * 40);

    for (int s0 = c0; s0 < c0 + CHUNK; s0 += 32) {
        __syncthreads();                              // prev iter LDS reads done
        for (int i = 0; i < 2; i++) {
            int ch = i * 256 + wave * 64 + lane;      // 0..511
            int kr = ch >> 4, kc8 = ch & 15;
            async16(k + (b * 2048 + s0 + kr) * 128 + kc8 * 8,
                    &ks[(i * 256 + wave * 64) * 8]);
            int vr = ch >> 2, vc8 = ch & 3;
            async16(vt + (b * 128 + vr) * 2048 + s0 + vc8 * 8,
                    &vs[(i * 256 + wave * 64) * 8]);
        }
        __syncthreads();                              // tiles visible

        // S = Q K^T: kb reused across both m-frags
        f32x4 Sf[2][2];
        for (int m = 0; m < 2; m++)
            for (int ct = 0; ct < 2; ct++) Sf[m][ct] = (f32x4){0.f, 0.f, 0.f, 0.f};
        for (int ct = 0; ct < 2; ct++)
            for (int c = 0; c < 4; c++) {
                bf16x8 kb = *(const bf16x8*)&ks[(ct * 16 + l16) * 128 + c * 32 + quad * 8];
                for (int m = 0; m < 2; m++)
                    Sf[m][ct] = __builtin_amdgcn_mfma_f32_16x16x32_bf16(
                        qf[m][c], kb, Sf[m][ct], 0, 0, 0);
            }

        // streaming softmax + P relayout (C-layout -> A-layout via wave LDS)
        for (int m = 0; m < 2; m++)
            for (int r = 0; r < 4; r++) {
                float p0 = __expf(Sf[m][0][r] - 10.0f);
                float p1 = __expf(Sf[m][1][r] - 10.0f);
                l_[m][r] += p0 + p1;
                psw[(m * 16 + quad * 4 + r) * 40 + l16]      = f2bf(p0);
                psw[(m * 16 + quad * 4 + r) * 40 + l16 + 16] = f2bf(p1);
            }
        __builtin_amdgcn_wave_barrier();
        __asm__ volatile("" ::: "memory");
        bf16x8 pf[2];
        for (int m = 0; m < 2; m++)
            pf[m] = *(const bf16x8*)&psw[(m * 16 + l16) * 40 + quad * 8];
        for (int t = 0; t < 8; t++) {
            bf16x8 vb = *(const bf16x8*)&vs[(t * 16 + l16) * 32 + quad * 8];
            for (int m = 0; m < 2; m++)
                O[m][t] = __builtin_amdgcn_mfma_f32_16x16x32_bf16(pf[m], vb, O[m][t], 0, 0, 0);
        }
        __builtin_amdgcn_wave_barrier();
        __asm__ volatile("" ::: "memory");
    }

    // l partials: reduce over the 16 lanes of each quad, one atomic per row
    for (int m = 0; m < 2; m++)
        for (int r = 0; r < 4; r++) {
            float lv = l_[m][r];
            lv += __shfl_xor(lv, 1);
            lv += __shfl_xor(lv, 2);
            lv += __shfl_xor(lv, 4);
            lv += __shfl_xor(lv, 8);
            if (l16 == 0)
                atomicAdd(&l_buf[b * 2048 + q0 + wave * 32 + m * 16 + quad * 4 + r], lv);
        }
    // O partials: C-layout row quad*4+r, col t*16+l16
    for (int m = 0; m < 2; m++)
        for (int t = 0; t < 8; t++)
            for (int r = 0; r < 4; r++) {
                int row = q0 + wave * 32 + m * 16 + quad * 4 + r;
                atomicAdd(&O_acc[(b * 2048 + row) * 128 + t * 16 + l16], O[m][t][r]);
            }
}

// ---------------------------------------------------------------------------
// Kernel 2b: combine — accum[b][d] += sum_s O_acc[b][s][d] / l_buf[b][s]
// ---------------------------------------------------------------------------
__global__ void combine(const float* __restrict__ O_acc, const float* __restrict__ l_buf,
                        float* __restrict__ accum)
{
    const int b   = blockIdx.y;
    const int s0  = blockIdx.x * 64 + (threadIdx.x >> 7) * 32;
    const int col = threadIdx.x & 127;
    float sum = 0.f;
    for (int i = 0; i < 32; i++) {
        int s = s0 + i;
        sum += O_acc[(b * 2048 + s) * 128 + col] / l_buf[b * 2048 + s];
    }
    atomicAdd(&accum[b * 128 + col], sum);
}

// ---------------------------------------------------------------------------
// Kernel 3: out[b][c] = (accum[b][:]/2048) . Wl[:,c] + bl[c], fp32 out.
// ---------------------------------------------------------------------------
__global__ void final_proj(const float* __restrict__ accum, const float* __restrict__ Wl,
                           const float* __restrict__ bl, float* __restrict__ out)
{
    int id = blockIdx.x * 256 + threadIdx.x;
    if (id >= NB * CC) return;
    int b = id / CC, c = id % CC;
    float s = 0.f;
    for (int d = 0; d < 128; d++)
        s += accum[b * 128 + d] * Wl[d * 1000 + c];
    out[id] = s * (1.0f / 2048.0f) + bl[c];
}

// ---------------------------------------------------------------------------
extern "C" void kernel_launch(void* const* d_in, const int* in_sizes, int n_in,
                              void* d_out, int out_size, void* d_ws, size_t ws_size,
                              hipStream_t stream) {
    const float* x  = (const float*)d_in[0];
    const float* Wq = (const float*)d_in[1];
    const float* bq = (const float*)d_in[2];
    const float* Wk = (const float*)d_in[3];
    const float* bk = (const float*)d_in[4];
    const float* Wv = (const float*)d_in[5];
    const float* bv = (const float*)d_in[6];
    const float* Wl = (const float*)d_in[7];
    const float* bl = (const float*)d_in[8];
    float* out = (float*)d_out;

    char* ws = (char*)d_ws;
    short* qo    = (short*)(ws);                 // 4 MiB
    short* ko    = (short*)(ws + 4194304);       // 4 MiB
    short* vto   = (short*)(ws + 8388608);       // 4 MiB, [b][d][s]
    short* xb    = (short*)(ws + 12582912);      // 16 MiB (x as bf16)
    short* Wt    = (short*)(ws + 29360128);      // 384 KiB
    float* O_acc = (float*)(ws + 29753344);      // 8 MiB
    float* l_buf = (float*)(ws + 38141952);      // 64 KiB
    float* acc   = (float*)(ws + 38207488);      // 4 KiB

    hipMemsetAsync(O_acc, 0, (size_t)NB * SS * DD * sizeof(float), stream);
    hipMemsetAsync(l_buf, 0, (size_t)NB * SS * sizeof(float), stream);
    hipMemsetAsync(acc,   0, (size_t)NB * DD * sizeof(float), stream);
    prep<<<4864, 256, 0, stream>>>(x, Wq, Wk, Wv, xb, Wt);
    qkv_proj<<<dim3(128, 3), 256, 0, stream>>>(xb, Wt, bq, bk, bv, qo, ko, vto);
    flash_partial<<<dim3(16, 8, KC), 256, 0, stream>>>(qo, ko, vto, O_acc, l_buf);
    combine<<<dim3(32, 8), 256, 0, stream>>>(O_acc, l_buf, acc);
    final_proj<<<(NB * CC + 255) / 256, 256, 0, stream>>>(acc, Wl, bl, out);
}

// Round 5
// 195.985 us; speedup vs baseline: 1.0836x; 1.0836x over previous
//
#include <hip/hip_runtime.h>
#include <stdint.h>

// B=8, S=2048, F=512, D=128, C=1000. I/O fp32; internal bf16 MFMA, fp32 accum.
#define NB 8
#define SS 2048
#define FF 512
#define DD 128
#define CC 1000
#define KC 8              // KV split factor (was 4; round-5 experiment: occupancy)
#define CHUNK (SS / KC)   // 256

typedef __attribute__((ext_vector_type(8))) short bf16x8;   // 8 bf16 = 4 VGPRs (MFMA A/B frag)
typedef __attribute__((ext_vector_type(4))) short bf16x4;   // 8 bytes
typedef __attribute__((ext_vector_type(4))) float f32x4;    // MFMA C/D frag

__device__ __forceinline__ short f2bf(float f) {
    uint32_t u;
    __builtin_memcpy(&u, &f, 4);
    u = (u + 0x7fffu + ((u >> 16) & 1u)) >> 16;   // RNE
    return (short)u;
}

// ---------------------------------------------------------------------------
// Kernel 0: transpose + bf16-cast projection weights [F][D]f32 -> [D][F]bf16.
// ---------------------------------------------------------------------------
__global__ void transpose_w(const float* __restrict__ Wq, const float* __restrict__ Wk,
                            const float* __restrict__ Wv, short* __restrict__ Wt) {
    int id = blockIdx.x * 256 + threadIdx.x;      // 0 .. 3*65536-1
    int w   = id >> 16;
    int rem = id & 65535;
    int n  = rem >> 9;                            // 0..127 (D)
    int kx = rem & 511;                           // 0..511 (F)
    const float* Wsrc = (w == 0) ? Wq : (w == 1) ? Wk : Wv;
    Wt[w * 65536 + n * 512 + kx] = f2bf(Wsrc[kx * 128 + n]);
}

// ---------------------------------------------------------------------------
// Kernel 1: fused QKV projection.  C[16384 x 128] = x[16384 x 512] @ W + bias.
// grid = (128 m-tiles, 3 matrices). 128x128 tile, BK=64, 4 waves each 64x64.
// Padded LDS (72 = odd 16B stride) -> fragment reads ~conflict-free.
// V stored transposed vt[b][d][s] for the PV B-operand.
// ---------------------------------------------------------------------------
__global__ __launch_bounds__(256) void qkv_proj(
    const float* __restrict__ x, const short* __restrict__ Wt,
    const float* __restrict__ bq, const float* __restrict__ bk, const float* __restrict__ bv,
    short* __restrict__ qo, short* __restrict__ ko, short* __restrict__ vto)
{
    __shared__ __align__(16) short As[128 * 72];
    __shared__ __align__(16) short Bs[128 * 72];

    const int m0   = blockIdx.x * 128;
    const int mat  = blockIdx.y;
    const int tid  = threadIdx.x;
    const int wave = tid >> 6, lane = tid & 63;
    const int quad = lane >> 4, l16 = lane & 15;
    const int wr = wave >> 1, wc = wave & 1;      // 2x2 wave quadrants

    const short* Wm = Wt + mat * 65536;

    f32x4 acc[4][4];
    for (int i = 0; i < 4; i++)
        for (int j = 0; j < 4; j++) acc[i][j] = (f32x4){0.f, 0.f, 0.f, 0.f};

    for (int kk = 0; kk < 512; kk += 64) {
        float4 a4[8];
        for (int i = 0; i < 8; i++) {
            int cid = i * 256 + tid;              // 0..2047
            int r_  = cid >> 4;                   // 0..127
            int kin = (cid & 15) * 4;             // 0..60
            a4[i] = *(const float4*)(x + (m0 + r_) * 512 + kk + kin);
        }
        bf16x8 bv_[4];
        for (int i = 0; i < 4; i++) {
            int cid = i * 256 + tid;              // 0..1023
            int r_  = cid >> 3;                   // 0..127
            int kin = (cid & 7) * 8;              // 0..56
            bv_[i] = *(const bf16x8*)(Wm + r_ * 512 + kk + kin);
        }
        __syncthreads();                          // prior iter's LDS reads done
        for (int i = 0; i < 8; i++) {
            int cid = i * 256 + tid;
            int r_  = cid >> 4;
            int kin = (cid & 15) * 4;
            bf16x4 s;
            s[0] = f2bf(a4[i].x); s[1] = f2bf(a4[i].y);
            s[2] = f2bf(a4[i].z); s[3] = f2bf(a4[i].w);
            *(bf16x4*)&As[r_ * 72 + kin] = s;
        }
        for (int i = 0; i < 4; i++) {
            int cid = i * 256 + tid;
            int r_  = cid >> 3;
            int kin = (cid & 7) * 8;
            *(bf16x8*)&Bs[r_ * 72 + kin] = bv_[i];
        }
        __syncthreads();

        for (int kc = 0; kc < 2; kc++) {
            bf16x8 af[4], bfr[4];
            for (int mt = 0; mt < 4; mt++)
                af[mt]  = *(const bf16x8*)&As[(wr * 64 + mt * 16 + l16) * 72 + kc * 32 + quad * 8];
            for (int nt = 0; nt < 4; nt++)
                bfr[nt] = *(const bf16x8*)&Bs[(wc * 64 + nt * 16 + l16) * 72 + kc * 32 + quad * 8];
            for (int mt = 0; mt < 4; mt++)
                for (int nt = 0; nt < 4; nt++)
                    acc[mt][nt] = __builtin_amdgcn_mfma_f32_16x16x32_bf16(
                        af[mt], bfr[nt], acc[mt][nt], 0, 0, 0);
        }
    }

    const float* bias = (mat == 0) ? bq : (mat == 1) ? bk : bv;
    for (int mt = 0; mt < 4; mt++) {
        int grow_base = m0 + wr * 64 + mt * 16 + quad * 4;   // C/D row = quad*4+reg
        for (int nt = 0; nt < 4; nt++) {
            int col = wc * 64 + nt * 16 + l16;               // C/D col = lane&15
            float bb = bias[col];
            for (int r = 0; r < 4; r++) {
                int grow = grow_base + r;
                short h = f2bf(acc[mt][nt][r] + bb);
                if (mat == 0)      qo[grow * 128 + col] = h;
                else if (mat == 1) ko[grow * 128 + col] = h;
                else {
                    int b_ = grow >> 11, si = grow & 2047;
                    vto[(b_ * 128 + col) * 2048 + si] = h;   // transposed V
                }
            }
        }
    }
}

// ---------------------------------------------------------------------------
// Kernel 2: split-KV flash attention with STREAMING softmax (fixed shift 10,
// no online max: logits bounded ~22 << 88; the e^-10 cancels in O/l).
// Round-3 proven structure (padded LDS, 64 q-rows, VGPR 48); KC=8 for
// occupancy: grid = (32 q-tiles, 8 batches, 8 chunks) = 2048 blocks.
// ---------------------------------------------------------------------------
__global__ __launch_bounds__(256) void flash_partial(
    const short* __restrict__ q, const short* __restrict__ k,
    const short* __restrict__ vt, float* __restrict__ O_acc,
    float* __restrict__ l_buf)
{
    __shared__ __align__(16) short ks[32 * 136];      // [kv][d]    pad 128->136
    __shared__ __align__(16) short vs[128 * 40];      // [d][kv]    pad 32->40
    __shared__ __align__(16) short ps[4 * 16 * 40];   // per-wave P [16][40]

    const int b   = blockIdx.y;
    const int q0  = blockIdx.x * 64;
    const int c0  = blockIdx.z * CHUNK;
    const int tid  = threadIdx.x;
    const int wave = tid >> 6, lane = tid & 63;
    const int quad = lane >> 4, l16 = lane & 15;
    const int qrow = q0 + wave * 16 + l16;            // A-operand row for this lane

    // persistent Q fragments: A[m=lane&15][k=quad*8+j], 4 chunks cover D=128
    bf16x8 qf[4];
    for (int c = 0; c < 4; c++)
        qf[c] = *(const bf16x8*)(q + (b * 2048 + qrow) * 128 + c * 32 + quad * 8);

    f32x4 O[8];                                       // 8 d-col tiles of 16
    for (int t = 0; t < 8; t++) O[t] = (f32x4){0.f, 0.f, 0.f, 0.f};
    float l_[4] = {0.f, 0.f, 0.f, 0.f};

    short* psw = ps + wave * (16 * 40);

    for (int s0 = c0; s0 < c0 + CHUNK; s0 += 32) {
        // stage K tile 32x128 and Vt tile 128x32 (512 16B-chunks each)
        bf16x8 kl[2], vl[2];
        for (int i = 0; i < 2; i++) {
            int cid = i * 256 + tid;                  // 0..511
            int kr = cid >> 4, kin = (cid & 15) * 8;
            kl[i] = *(const bf16x8*)(k + (b * 2048 + s0 + kr) * 128 + kin);
            int vr = cid >> 2, sin = (cid & 3) * 8;
            vl[i] = *(const bf16x8*)(vt + (b * 128 + vr) * 2048 + s0 + sin);
        }
        __syncthreads();                              // prior iter LDS reads done
        for (int i = 0; i < 2; i++) {
            int cid = i * 256 + tid;
            int kr = cid >> 4, kin = (cid & 15) * 8;
            *(bf16x8*)&ks[kr * 136 + kin] = kl[i];
            int vr = cid >> 2, sin = (cid & 3) * 8;
            *(bf16x8*)&vs[vr * 40 + sin] = vl[i];
        }
        __syncthreads();

        // S = Q K^T for two 16-col tiles (kv cols s0..s0+31)
        f32x4 Sf[2];
        for (int ct = 0; ct < 2; ct++) {
            Sf[ct] = (f32x4){0.f, 0.f, 0.f, 0.f};
            for (int c = 0; c < 4; c++) {
                bf16x8 kb = *(const bf16x8*)&ks[(ct * 16 + l16) * 136 + c * 32 + quad * 8];
                Sf[ct] = __builtin_amdgcn_mfma_f32_16x16x32_bf16(qf[c], kb, Sf[ct], 0, 0, 0);
            }
        }

        // streaming softmax: P = exp(S - 10), accumulate row-sum partials
        float P0[4], P1[4];
        for (int r = 0; r < 4; r++) {
            P0[r] = __expf(Sf[0][r] - 10.0f);
            P1[r] = __expf(Sf[1][r] - 10.0f);
            l_[r] += P0[r] + P1[r];
        }

        // P: C-layout -> A-layout through per-wave LDS (wave-local; fence
        // stops compiler reordering, same-wave DS ops are in-order)
        for (int r = 0; r < 4; r++) {
            psw[(quad * 4 + r) * 40 + l16]      = f2bf(P0[r]);
            psw[(quad * 4 + r) * 40 + l16 + 16] = f2bf(P1[r]);
        }
        __builtin_amdgcn_wave_barrier();
        __asm__ volatile("" ::: "memory");
        bf16x8 pf = *(const bf16x8*)&psw[l16 * 40 + quad * 8];
        for (int t = 0; t < 8; t++) {
            bf16x8 vb = *(const bf16x8*)&vs[(t * 16 + l16) * 40 + quad * 8];
            O[t] = __builtin_amdgcn_mfma_f32_16x16x32_bf16(pf, vb, O[t], 0, 0, 0);
        }
        __builtin_amdgcn_wave_barrier();
        __asm__ volatile("" ::: "memory");
    }

    // merge partials: l_[r] holds row (quad*4+r) summed over this lane's cols;
    // reduce over the 16 lanes of the quad, then one atomic per row.
    for (int r = 0; r < 4; r++) {
        float lv = l_[r];
        lv += __shfl_xor(lv, 1);
        lv += __shfl_xor(lv, 2);
        lv += __shfl_xor(lv, 4);
        lv += __shfl_xor(lv, 8);
        if (l16 == 0)
            atomicAdd(&l_buf[b * 2048 + q0 + wave * 16 + quad * 4 + r], lv);
    }
    // O partials: C-layout row quad*4+r, col t*16+l16
    for (int t = 0; t < 8; t++)
        for (int r = 0; r < 4; r++) {
            int row = q0 + wave * 16 + quad * 4 + r;
            atomicAdd(&O_acc[(b * 2048 + row) * 128 + t * 16 + l16], O[t][r]);
        }
}

// ---------------------------------------------------------------------------
// Kernel 2b: combine — accum[b][d] += sum_s O_acc[b][s][d] / l_buf[b][s]
// ---------------------------------------------------------------------------
__global__ void combine(const float* __restrict__ O_acc, const float* __restrict__ l_buf,
                        float* __restrict__ accum)
{
    const int b   = blockIdx.y;
    const int s0  = blockIdx.x * 64 + (threadIdx.x >> 7) * 32;
    const int col = threadIdx.x & 127;
    float sum = 0.f;
    for (int i = 0; i < 32; i++) {
        int s = s0 + i;
        sum += O_acc[(b * 2048 + s) * 128 + col] / l_buf[b * 2048 + s];
    }
    atomicAdd(&accum[b * 128 + col], sum);
}

// ---------------------------------------------------------------------------
// Kernel 3: out[b][c] = (accum[b][:]/2048) . Wl[:,c] + bl[c], fp32 out.
// ---------------------------------------------------------------------------
__global__ void final_proj(const float* __restrict__ accum, const float* __restrict__ Wl,
                           const float* __restrict__ bl, float* __restrict__ out)
{
    int id = blockIdx.x * 256 + threadIdx.x;
    if (id >= NB * CC) return;
    int b = id / CC, c = id % CC;
    float s = 0.f;
    for (int d = 0; d < 128; d++)
        s += accum[b * 128 + d] * Wl[d * 1000 + c];
    out[id] = s * (1.0f / 2048.0f) + bl[c];
}

// ---------------------------------------------------------------------------
extern "C" void kernel_launch(void* const* d_in, const int* in_sizes, int n_in,
                              void* d_out, int out_size, void* d_ws, size_t ws_size,
                              hipStream_t stream) {
    const float* x  = (const float*)d_in[0];
    const float* Wq = (const float*)d_in[1];
    const float* bq = (const float*)d_in[2];
    const float* Wk = (const float*)d_in[3];
    const float* bk = (const float*)d_in[4];
    const float* Wv = (const float*)d_in[5];
    const float* bv = (const float*)d_in[6];
    const float* Wl = (const float*)d_in[7];
    const float* bl = (const float*)d_in[8];
    float* out = (float*)d_out;

    char* ws = (char*)d_ws;
    short* qo    = (short*)(ws);                 // 4 MiB
    short* ko    = (short*)(ws + 4194304);       // 4 MiB
    short* vto   = (short*)(ws + 8388608);       // 4 MiB, [b][d][s]
    short* Wt    = (short*)(ws + 12582912);      // 384 KiB
    float* O_acc = (float*)(ws + 13107200);      // 8 MiB
    float* l_buf = (float*)(ws + 21495808);      // 64 KiB
    float* acc   = (float*)(ws + 21561344);      // 4 KiB

    hipMemsetAsync(O_acc, 0, (size_t)NB * SS * DD * sizeof(float), stream);
    hipMemsetAsync(l_buf, 0, (size_t)NB * SS * sizeof(float), stream);
    hipMemsetAsync(acc,   0, (size_t)NB * DD * sizeof(float), stream);
    transpose_w<<<768, 256, 0, stream>>>(Wq, Wk, Wv, Wt);
    qkv_proj<<<dim3(128, 3), 256, 0, stream>>>(x, Wt, bq, bk, bv, qo, ko, vto);
    flash_partial<<<dim3(32, 8, KC), 256, 0, stream>>>(qo, ko, vto, O_acc, l_buf);
    combine<<<dim3(32, 8), 256, 0, stream>>>(O_acc, l_buf, acc);
    final_proj<<<(NB * CC + 255) / 256, 256, 0, stream>>>(acc, Wl, bl, out);
}

// Round 6
// 170.947 us; speedup vs baseline: 1.2423x; 1.1465x over previous
//
#include <hip/hip_runtime.h>
#include <stdint.h>

// B=8, S=2048, F=512, D=128, C=1000. I/O fp32; internal bf16 MFMA, fp32 accum.
// LDS tiles are stored as XOR-swizzled 16B chunks: chunk (r,c) of a tile with
// C chunks/row lives at position r*C + (c ^ (r & (C-1)))  (capped masks per
// tile, chosen so every MFMA fragment read is <=2-way bank aliased = free),
// which keeps global_load_lds's contiguous-dest constraint satisfied.
#define NB 8
#define SS 2048
#define FF 512
#define DD 128
#define CC 1000
#define KC 8              // KV split factor
#define CHUNK (SS / KC)   // 256

typedef __attribute__((ext_vector_type(8))) short bf16x8;
typedef __attribute__((ext_vector_type(4))) float f32x4;

__device__ __forceinline__ short f2bf(float f) {
    uint32_t u;
    __builtin_memcpy(&u, &f, 4);
    u = (u + 0x7fffu + ((u >> 16) & 1u)) >> 16;   // RNE
    return (short)u;
}
__device__ __forceinline__ float bf2f(short h) {
    uint32_t u = ((uint32_t)(uint16_t)h) << 16;
    float f;
    __builtin_memcpy(&f, &u, 4);
    return f;
}
// async 16B global->LDS; LDS dest = wave-uniform base + lane*16
__device__ __forceinline__ void async16(const void* g, void* l) {
    __builtin_amdgcn_global_load_lds(
        (const __attribute__((address_space(1))) uint32_t*)g,
        (__attribute__((address_space(3))) uint32_t*)l, 16, 0, 0);
}

// ---------------------------------------------------------------------------
// Kernel 0 (prep): cast x fp32->bf16 (blocks 0..4095) and transpose+cast the
// projection weights [F][D]f32 -> [D][F]bf16 (blocks 4096..4863).
// ---------------------------------------------------------------------------
__global__ void prep(const float* __restrict__ x,
                     const float* __restrict__ Wq, const float* __restrict__ Wk,
                     const float* __restrict__ Wv,
                     short* __restrict__ xb, short* __restrict__ Wt)
{
    int bx = blockIdx.x;
    if (bx < 4096) {
        int id = bx * 256 + threadIdx.x;
        const float4* src = (const float4*)x + id * 2;
        float4 a = src[0], b2 = src[1];
        bf16x8 o;
        o[0] = f2bf(a.x);  o[1] = f2bf(a.y);  o[2] = f2bf(a.z);  o[3] = f2bf(a.w);
        o[4] = f2bf(b2.x); o[5] = f2bf(b2.y); o[6] = f2bf(b2.z); o[7] = f2bf(b2.w);
        *(bf16x8*)(xb + id * 8) = o;
    } else {
        int id = (bx - 4096) * 256 + threadIdx.x;
        int w = id >> 16, rem = id & 65535;
        int n = rem >> 9, kx = rem & 511;
        const float* Wsrc = (w == 0) ? Wq : (w == 1) ? Wk : Wv;
        Wt[w * 65536 + n * 512 + kx] = f2bf(Wsrc[kx * 128 + n]);
    }
}

// ---------------------------------------------------------------------------
// Kernel 1: fused QKV projection via swizzled global_load_lds.
// C[16384x128] = xb[16384x512] @ Wt^T + bias. grid (128 m-tiles, 3 mats).
// Tile 128x128, BK=64 (8 chunks/row). V stored transposed vt[b][d][s].
// ---------------------------------------------------------------------------
__global__ __launch_bounds__(256) void qkv_proj(
    const short* __restrict__ xb, const short* __restrict__ Wt,
    const float* __restrict__ bq, const float* __restrict__ bk, const float* __restrict__ bv,
    short* __restrict__ qo, short* __restrict__ ko, short* __restrict__ vto)
{
    __shared__ __align__(16) short As[128 * 64];   // swizzled chunks, C=8
    __shared__ __align__(16) short Bs[128 * 64];

    const int m0   = blockIdx.x * 128;
    const int mat  = blockIdx.y;
    const int tid  = threadIdx.x;
    const int wave = tid >> 6, lane = tid & 63;
    const int quad = lane >> 4, l16 = lane & 15;
    const int wr = wave >> 1, wc = wave & 1;

    const short* Wm = Wt + mat * 65536;

    f32x4 acc[4][4];
    for (int i = 0; i < 4; i++)
        for (int j = 0; j < 4; j++) acc[i][j] = (f32x4){0.f, 0.f, 0.f, 0.f};

    // staging source (per lane, per instruction ins): row 8*ins + lane>>3,
    // chunk c = (lane&7) ^ ((lane>>3)&7)  [since (8*ins)&7 == 0]
    const int sr = lane >> 3;
    const int sc = (lane & 7) ^ (sr & 7);

    for (int kk = 0; kk < 512; kk += 64) {
        __syncthreads();                           // prior iter frag reads done
        for (int i = 0; i < 4; i++) {
            int ins = wave * 4 + i;                // 0..15
            int r = ins * 8 + sr;
            async16(xb + (m0 + r) * 512 + kk + sc * 8, &As[ins * 512]);
            async16(Wm + r * 512 + kk + sc * 8,        &Bs[ins * 512]);
        }
        __syncthreads();                           // vmcnt drained -> visible

        for (int kc = 0; kc < 2; kc++) {
            bf16x8 af[4], bfr[4];
            for (int mt = 0; mt < 4; mt++) {
                int R = wr * 64 + mt * 16 + l16, cc = kc * 4 + quad;
                af[mt] = *(const bf16x8*)&As[(R * 8 + (cc ^ (R & 7))) * 8];
            }
            for (int nt = 0; nt < 4; nt++) {
                int R = wc * 64 + nt * 16 + l16, cc = kc * 4 + quad;
                bfr[nt] = *(const bf16x8*)&Bs[(R * 8 + (cc ^ (R & 7))) * 8];
            }
            for (int mt = 0; mt < 4; mt++)
                for (int nt = 0; nt < 4; nt++)
                    acc[mt][nt] = __builtin_amdgcn_mfma_f32_16x16x32_bf16(
                        af[mt], bfr[nt], acc[mt][nt], 0, 0, 0);
        }
    }

    const float* bias = (mat == 0) ? bq : (mat == 1) ? bk : bv;
    for (int mt = 0; mt < 4; mt++) {
        int grow_base = m0 + wr * 64 + mt * 16 + quad * 4;   // C/D row = quad*4+reg
        for (int nt = 0; nt < 4; nt++) {
            int col = wc * 64 + nt * 16 + l16;               // C/D col = lane&15
            float bb = bias[col];
            for (int r = 0; r < 4; r++) {
                int grow = grow_base + r;
                short h = f2bf(acc[mt][nt][r] + bb);
                if (mat == 0)      qo[grow * 128 + col] = h;
                else if (mat == 1) ko[grow * 128 + col] = h;
                else {
                    int b_ = grow >> 11, si = grow & 2047;
                    vto[(b_ * 128 + col) * 2048 + si] = h;   // transposed V
                }
            }
        }
    }
}

// ---------------------------------------------------------------------------
// Kernel 2: split-KV flash attention, streaming softmax (fixed shift 10; the
// e^-10 cancels in O/l; logits bounded ~22 << 88). 128 q-rows/block: 4 waves
// x 2 m-frags -> K/V fragment reads per MFMA halved. Swizzled glds staging.
// Epilogue: PLAIN stores of bf16 O partials + fp32 l partials (no atomics).
// grid = (16 q-tiles, 8 batches, KC chunks) = 1024 blocks.
// ---------------------------------------------------------------------------
__global__ __launch_bounds__(256) void flash_partial(
    const short* __restrict__ q, const short* __restrict__ k,
    const short* __restrict__ vt, short* __restrict__ O_part,
    float* __restrict__ l_part)
{
    __shared__ __align__(16) short ks[32 * 128];      // [kv][d] swizzled, C=16
    __shared__ __align__(16) short vs[128 * 32];      // [d][kv] swizzled, C=4
    __shared__ __align__(16) short ps[4 * 32 * 40];   // per-wave P [32][40]

    const int b   = blockIdx.y;
    const int q0  = blockIdx.x * 128;
    const int lq  = blockIdx.z;
    const int c0  = lq * CHUNK;
    const int tid  = threadIdx.x;
    const int wave = tid >> 6, lane = tid & 63;
    const int quad = lane >> 4, l16 = lane & 15;

    // persistent Q fragments, 2 m-tiles: A[m=lane&15][k=quad*8+j]
    bf16x8 qf[2][4];
    for (int m = 0; m < 2; m++)
        for (int c = 0; c < 4; c++)
            qf[m][c] = *(const bf16x8*)(q + (b * 2048 + q0 + wave * 32 + m * 16 + l16) * 128
                                          + c * 32 + quad * 8);

    f32x4 O[2][8];
    for (int m = 0; m < 2; m++)
        for (int t = 0; t < 8; t++) O[m][t] = (f32x4){0.f, 0.f, 0.f, 0.f};
    float l_[2][4] = {{0.f,0.f,0.f,0.f},{0.f,0.f,0.f,0.f}};

    short* psw = ps + wave * (32 * 40);

    // staging source offsets (per lane, per instruction ik):
    // K: row 4*ik + (lane>>4), chunk c = (lane&15) ^ (row&15)
    // V: row 16*ik + (lane>>2), chunk c = (lane&3) ^ ((lane>>3)&3)
    const int krl = lane >> 4;
    const int vrl = lane >> 2;
    const int vcl = (lane & 3) ^ ((lane >> 3) & 3);

    for (int s0 = c0; s0 < c0 + CHUNK; s0 += 32) {
        __syncthreads();                              // prior iter reads done
        for (int i2 = 0; i2 < 2; i2++) {
            int ik = wave * 2 + i2;                   // 0..7
            int kr = 4 * ik + krl;
            int kc8 = (lane & 15) ^ (kr & 15);
            async16(k + (b * 2048 + s0 + kr) * 128 + kc8 * 8, &ks[ik * 512]);
            int vr = 16 * ik + vrl;
            async16(vt + (b * 128 + vr) * 2048 + s0 + vcl * 8, &vs[ik * 512]);
        }
        __syncthreads();                              // vmcnt drained

        // S = Q K^T (kb reused across both m-frags)
        f32x4 Sf[2][2];
        for (int m = 0; m < 2; m++)
            for (int ct = 0; ct < 2; ct++) Sf[m][ct] = (f32x4){0.f, 0.f, 0.f, 0.f};
        for (int ct = 0; ct < 2; ct++) {
            int R = ct * 16 + l16;                    // R&15 == l16
            for (int c = 0; c < 4; c++) {
                int cc = c * 4 + quad;
                bf16x8 kb = *(const bf16x8*)&ks[(R * 16 + (cc ^ l16)) * 8];
                for (int m = 0; m < 2; m++)
                    Sf[m][ct] = __builtin_amdgcn_mfma_f32_16x16x32_bf16(
                        qf[m][c], kb, Sf[m][ct], 0, 0, 0);
            }
        }

        // streaming softmax + P relayout (C-layout -> A-layout via wave LDS)
        for (int m = 0; m < 2; m++)
            for (int r = 0; r < 4; r++) {
                float p0 = __expf(Sf[m][0][r] - 10.0f);
                float p1 = __expf(Sf[m][1][r] - 10.0f);
                l_[m][r] += p0 + p1;
                psw[(m * 16 + quad * 4 + r) * 40 + l16]      = f2bf(p0);
                psw[(m * 16 + quad * 4 + r) * 40 + l16 + 16] = f2bf(p1);
            }
        __builtin_amdgcn_wave_barrier();
        __asm__ volatile("" ::: "memory");
        bf16x8 pf[2];
        for (int m = 0; m < 2; m++)
            pf[m] = *(const bf16x8*)&psw[(m * 16 + l16) * 40 + quad * 8];
        for (int t = 0; t < 8; t++) {
            int R = t * 16 + l16;                     // (R>>1)&3 == (l16>>1)&3
            bf16x8 vb = *(const bf16x8*)&vs[(R * 4 + (quad ^ ((l16 >> 1) & 3))) * 8];
            for (int m = 0; m < 2; m++)
                O[m][t] = __builtin_amdgcn_mfma_f32_16x16x32_bf16(pf[m], vb, O[m][t], 0, 0, 0);
        }
        __builtin_amdgcn_wave_barrier();
        __asm__ volatile("" ::: "memory");
    }

    // epilogue: PLAIN stores (each (lq,b,row[,d]) written by exactly one lane)
    const int base = (lq * 8 + b) * 2048;
    for (int m = 0; m < 2; m++)
        for (int r = 0; r < 4; r++) {
            float lv = l_[m][r];
            lv += __shfl_xor(lv, 1);
            lv += __shfl_xor(lv, 2);
            lv += __shfl_xor(lv, 4);
            lv += __shfl_xor(lv, 8);
            if (l16 == 0)
                l_part[base + q0 + wave * 32 + m * 16 + quad * 4 + r] = lv;
        }
    for (int m = 0; m < 2; m++)
        for (int t = 0; t < 8; t++)
            for (int r = 0; r < 4; r++) {
                int row = q0 + wave * 32 + m * 16 + quad * 4 + r;
                O_part[(size_t)(base + row) * 128 + t * 16 + l16] = f2bf(O[m][t][r]);
            }
}

// ---------------------------------------------------------------------------
// Kernel 2b: combine — accum[b][d] += sum_s (sum_kc O_part) / (sum_kc l_part)
// ---------------------------------------------------------------------------
__global__ void combine(const short* __restrict__ O_part, const float* __restrict__ l_part,
                        float* __restrict__ accum)
{
    const int b   = blockIdx.y;
    const int s0  = blockIdx.x * 64 + (threadIdx.x >> 7) * 32;
    const int col = threadIdx.x & 127;
    float sum = 0.f;
    for (int i = 0; i < 32; i++) {
        int s = s0 + i;
        float l = 0.f, o = 0.f;
        for (int kc = 0; kc < KC; kc++) {
            int base = (kc * 8 + b) * 2048 + s;
            l += l_part[base];
            o += bf2f(O_part[(size_t)base * 128 + col]);
        }
        sum += o / l;
    }
    atomicAdd(&accum[b * 128 + col], sum);
}

// ---------------------------------------------------------------------------
// Kernel 3: out[b][c] = (accum[b][:]/2048) . Wl[:,c] + bl[c], fp32 out.
// ---------------------------------------------------------------------------
__global__ void final_proj(const float* __restrict__ accum, const float* __restrict__ Wl,
                           const float* __restrict__ bl, float* __restrict__ out)
{
    int id = blockIdx.x * 256 + threadIdx.x;
    if (id >= NB * CC) return;
    int b = id / CC, c = id % CC;
    float s = 0.f;
    for (int d = 0; d < 128; d++)
        s += accum[b * 128 + d] * Wl[d * 1000 + c];
    out[id] = s * (1.0f / 2048.0f) + bl[c];
}

// ---------------------------------------------------------------------------
extern "C" void kernel_launch(void* const* d_in, const int* in_sizes, int n_in,
                              void* d_out, int out_size, void* d_ws, size_t ws_size,
                              hipStream_t stream) {
    const float* x  = (const float*)d_in[0];
    const float* Wq = (const float*)d_in[1];
    const float* bq = (const float*)d_in[2];
    const float* Wk = (const float*)d_in[3];
    const float* bk = (const float*)d_in[4];
    const float* Wv = (const float*)d_in[5];
    const float* bv = (const float*)d_in[6];
    const float* Wl = (const float*)d_in[7];
    const float* bl = (const float*)d_in[8];
    float* out = (float*)d_out;

    char* ws = (char*)d_ws;
    short* qo     = (short*)(ws);                 // 4 MiB
    short* ko     = (short*)(ws + 4194304);       // 4 MiB
    short* vto    = (short*)(ws + 8388608);       // 4 MiB, [b][d][s]
    // xb (16 MiB, used by prep+qkv only) ALIASES O_part (32 MiB, used by
    // flash+combine only) — disjoint lifetimes on the sequential stream.
    short* xb     = (short*)(ws + 12582912);
    short* O_part = (short*)(ws + 12582912);      // 32 MiB (KC*8*2048*128 bf16)
    short* Wt     = (short*)(ws + 46137344);      // 384 KiB
    float* l_part = (float*)(ws + 46530560);      // 512 KiB (KC*8*2048 fp32)
    float* acc    = (float*)(ws + 47054848);      // 4 KiB
    // total ~45 MiB of d_ws

    hipMemsetAsync(acc, 0, NB * DD * sizeof(float), stream);
    prep<<<4864, 256, 0, stream>>>(x, Wq, Wk, Wv, xb, Wt);
    qkv_proj<<<dim3(128, 3), 256, 0, stream>>>(xb, Wt, bq, bk, bv, qo, ko, vto);
    flash_partial<<<dim3(16, 8, KC), 256, 0, stream>>>(qo, ko, vto, O_part, l_part);
    combine<<<dim3(32, 8), 256, 0, stream>>>(O_part, l_part, acc);
    final_proj<<<(NB * CC + 255) / 256, 256, 0, stream>>>(acc, Wl, bl, out);
}

// Round 9
// 160.752 us; speedup vs baseline: 1.3211x; 1.0634x over previous
//
#include <hip/hip_runtime.h>
#include <stdint.h>

// B=8, S=2048, F=512, D=128, C=1000. I/O fp32; internal bf16 MFMA, fp32 accum.
// mean-attention restructure: w[k] = sum_s exp(S[s,k]-10)/l[s];
// sum_s attn_out = w . V  -> no PV MFMA, no O partials, no combine.
// LDS tiles = XOR-swizzled 16B chunks: chunk (r,c) at r*C + (c ^ (r & (C-1))).
#define NB 8
#define SS 2048
#define FF 512
#define DD 128
#define CC 1000
#define KC 8              // KV split factor
#define CHUNK (SS / KC)   // 256

typedef __attribute__((ext_vector_type(8))) short bf16x8;
typedef __attribute__((ext_vector_type(4))) float f32x4;

__device__ __forceinline__ short f2bf(float f) {
    uint32_t u;
    __builtin_memcpy(&u, &f, 4);
    u = (u + 0x7fffu + ((u >> 16) & 1u)) >> 16;   // RNE
    return (short)u;
}
__device__ __forceinline__ float bf2f(short h) {
    uint32_t u = ((uint32_t)(uint16_t)h) << 16;
    float f;
    __builtin_memcpy(&f, &u, 4);
    return f;
}
// async 16B global->LDS; LDS dest = wave-uniform base + lane*16
__device__ __forceinline__ void async16(const void* g, void* l) {
    __builtin_amdgcn_global_load_lds(
        (const __attribute__((address_space(1))) uint32_t*)g,
        (__attribute__((address_space(3))) uint32_t*)l, 16, 0, 0);
}

// ---------------------------------------------------------------------------
// Kernel 0 (prep): cast x fp32->bf16 (blocks 0..4095) and transpose+cast the
// projection weights [F][D]f32 -> [D][F]bf16 (blocks 4096..4863).
// ---------------------------------------------------------------------------
__global__ void prep(const float* __restrict__ x,
                     const float* __restrict__ Wq, const float* __restrict__ Wk,
                     const float* __restrict__ Wv,
                     short* __restrict__ xb, short* __restrict__ Wt)
{
    int bx = blockIdx.x;
    if (bx < 4096) {
        int id = bx * 256 + threadIdx.x;
        const float4* src = (const float4*)x + id * 2;
        float4 a = src[0], b2 = src[1];
        bf16x8 o;
        o[0] = f2bf(a.x);  o[1] = f2bf(a.y);  o[2] = f2bf(a.z);  o[3] = f2bf(a.w);
        o[4] = f2bf(b2.x); o[5] = f2bf(b2.y); o[6] = f2bf(b2.z); o[7] = f2bf(b2.w);
        *(bf16x8*)(xb + id * 8) = o;
    } else {
        int id = (bx - 4096) * 256 + threadIdx.x;
        int w = id >> 16, rem = id & 65535;
        int n = rem >> 9, kx = rem & 511;
        const float* Wsrc = (w == 0) ? Wq : (w == 1) ? Wk : Wv;
        Wt[w * 65536 + n * 512 + kx] = f2bf(Wsrc[kx * 128 + n]);
    }
}

// ---------------------------------------------------------------------------
// Kernel 1: fused QKV projection via swizzled global_load_lds.
// C[16384x128] = xb[16384x512] @ Wt^T + bias. grid (128 m-tiles, 3 mats).
// V stored transposed vt[b][d][s].
// ---------------------------------------------------------------------------
__global__ __launch_bounds__(256) void qkv_proj(
    const short* __restrict__ xb, const short* __restrict__ Wt,
    const float* __restrict__ bq, const float* __restrict__ bk, const float* __restrict__ bv,
    short* __restrict__ qo, short* __restrict__ ko, short* __restrict__ vto)
{
    __shared__ __align__(16) short As[128 * 64];   // swizzled chunks, C=8
    __shared__ __align__(16) short Bs[128 * 64];

    const int m0   = blockIdx.x * 128;
    const int mat  = blockIdx.y;
    const int tid  = threadIdx.x;
    const int wave = tid >> 6, lane = tid & 63;
    const int quad = lane >> 4, l16 = lane & 15;
    const int wr = wave >> 1, wc = wave & 1;

    const short* Wm = Wt + mat * 65536;

    f32x4 acc[4][4];
    for (int i = 0; i < 4; i++)
        for (int j = 0; j < 4; j++) acc[i][j] = (f32x4){0.f, 0.f, 0.f, 0.f};

    const int sr = lane >> 3;
    const int sc = (lane & 7) ^ (sr & 7);

    for (int kk = 0; kk < 512; kk += 64) {
        __syncthreads();                           // prior iter frag reads done
        for (int i = 0; i < 4; i++) {
            int ins = wave * 4 + i;                // 0..15
            int r = ins * 8 + sr;
            async16(xb + (m0 + r) * 512 + kk + sc * 8, &As[ins * 512]);
            async16(Wm + r * 512 + kk + sc * 8,        &Bs[ins * 512]);
        }
        __syncthreads();                           // vmcnt drained -> visible

        for (int kc = 0; kc < 2; kc++) {
            bf16x8 af[4], bfr[4];
            for (int mt = 0; mt < 4; mt++) {
                int R = wr * 64 + mt * 16 + l16, cc = kc * 4 + quad;
                af[mt] = *(const bf16x8*)&As[(R * 8 + (cc ^ (R & 7))) * 8];
            }
            for (int nt = 0; nt < 4; nt++) {
                int R = wc * 64 + nt * 16 + l16, cc = kc * 4 + quad;
                bfr[nt] = *(const bf16x8*)&Bs[(R * 8 + (cc ^ (R & 7))) * 8];
            }
            for (int mt = 0; mt < 4; mt++)
                for (int nt = 0; nt < 4; nt++)
                    acc[mt][nt] = __builtin_amdgcn_mfma_f32_16x16x32_bf16(
                        af[mt], bfr[nt], acc[mt][nt], 0, 0, 0);
        }
    }

    const float* bias = (mat == 0) ? bq : (mat == 1) ? bk : bv;
    for (int mt = 0; mt < 4; mt++) {
        int grow_base = m0 + wr * 64 + mt * 16 + quad * 4;   // C/D row = quad*4+reg
        for (int nt = 0; nt < 4; nt++) {
            int col = wc * 64 + nt * 16 + l16;               // C/D col = lane&15
            float bb = bias[col];
            for (int r = 0; r < 4; r++) {
                int grow = grow_base + r;
                short h = f2bf(acc[mt][nt][r] + bb);
                if (mat == 0)      qo[grow * 128 + col] = h;
                else if (mat == 1) ko[grow * 128 + col] = h;
                else {
                    int b_ = grow >> 11, si = grow & 2047;
                    vto[(b_ * 128 + col) * 2048 + si] = h;   // transposed V
                }
            }
        }
    }
}

// ---------------------------------------------------------------------------
// Kernel 2 (pass 1): l_part[kc][b][row] = sum over this KV chunk of
// exp(q_row . k_s - 10).  128 q-rows/block (4 waves x 2 m-frags), KV tile 64.
// grid = (16 q-tiles, 8 batches, KC) = 1024 blocks.
// ---------------------------------------------------------------------------
__global__ __launch_bounds__(256) void attn_l(
    const short* __restrict__ q, const short* __restrict__ k,
    float* __restrict__ l_part)
{
    __shared__ __align__(16) short ks[64 * 128];      // swizzled, C=16

    const int b  = blockIdx.y;
    const int q0 = blockIdx.x * 128;
    const int lq = blockIdx.z;
    const int c0 = lq * CHUNK;
    const int tid  = threadIdx.x;
    const int wave = tid >> 6, lane = tid & 63;
    const int quad = lane >> 4, l16 = lane & 15;

    bf16x8 qf[2][4];
    for (int m = 0; m < 2; m++)
        for (int c = 0; c < 4; c++)
            qf[m][c] = *(const bf16x8*)(q + (b * 2048 + q0 + wave * 32 + m * 16 + l16) * 128
                                          + c * 32 + quad * 8);

    float lsum[2][4] = {{0.f,0.f,0.f,0.f},{0.f,0.f,0.f,0.f}};
    const int krl = lane >> 4;                        // 0..3

    for (int s0 = c0; s0 < c0 + CHUNK; s0 += 64) {
        __syncthreads();
        for (int i = 0; i < 4; i++) {
            int ik = wave * 4 + i;                    // 0..15
            int kr = ik * 4 + krl;                    // 0..63
            int kc8 = (lane & 15) ^ (kr & 15);
            async16(k + (b * 2048 + s0 + kr) * 128 + kc8 * 8, &ks[ik * 512]);
        }
        __syncthreads();

        for (int ct = 0; ct < 4; ct++) {
            f32x4 Sf[2];
            Sf[0] = (f32x4){0.f,0.f,0.f,0.f};
            Sf[1] = (f32x4){0.f,0.f,0.f,0.f};
            int R = ct * 16 + l16;                    // R&15 == l16
            for (int c = 0; c < 4; c++) {
                int cc = c * 4 + quad;
                bf16x8 kb = *(const bf16x8*)&ks[(R * 16 + (cc ^ l16)) * 8];
                for (int m = 0; m < 2; m++)
                    Sf[m] = __builtin_amdgcn_mfma_f32_16x16x32_bf16(
                        qf[m][c], kb, Sf[m], 0, 0, 0);
            }
            for (int m = 0; m < 2; m++)
                for (int r = 0; r < 4; r++)
                    lsum[m][r] += __expf(Sf[m][r] - 10.0f);
        }
    }

    for (int m = 0; m < 2; m++)
        for (int r = 0; r < 4; r++) {
            float lv = lsum[m][r];
            lv += __shfl_xor(lv, 1);
            lv += __shfl_xor(lv, 2);
            lv += __shfl_xor(lv, 4);
            lv += __shfl_xor(lv, 8);
            if (l16 == 0)
                l_part[(lq * 8 + b) * 2048 + q0 + wave * 32 + m * 16 + quad * 4 + r] = lv;
        }
}

// ---------------------------------------------------------------------------
// Kernel 3 (pass 2): w[b][k] += sum over this block's 128 q-rows of
// exp(S-10)/l_total[row].  Column sums staged per-wave in LDS; one atomicAdd
// per column per block.  grid = (16, 8, KC).
// ---------------------------------------------------------------------------
__global__ __launch_bounds__(256) void attn_w(
    const short* __restrict__ q, const short* __restrict__ k,
    const float* __restrict__ l_part, float* __restrict__ w)
{
    __shared__ __align__(16) short ks[64 * 128];      // swizzled, C=16
    __shared__ float wl[4][256];

    const int b  = blockIdx.y;
    const int q0 = blockIdx.x * 128;
    const int lq = blockIdx.z;
    const int c0 = lq * CHUNK;
    const int tid  = threadIdx.x;
    const int wave = tid >> 6, lane = tid & 63;
    const int quad = lane >> 4, l16 = lane & 15;

    bf16x8 qf[2][4];
    for (int m = 0; m < 2; m++)
        for (int c = 0; c < 4; c++)
            qf[m][c] = *(const bf16x8*)(q + (b * 2048 + q0 + wave * 32 + m * 16 + l16) * 128
                                          + c * 32 + quad * 8);

    float linv[2][4];
    for (int m = 0; m < 2; m++)
        for (int r = 0; r < 4; r++) {
            int row = q0 + wave * 32 + m * 16 + quad * 4 + r;
            float lt = 0.f;
            for (int kc = 0; kc < KC; kc++) lt += l_part[(kc * 8 + b) * 2048 + row];
            linv[m][r] = 1.0f / lt;
        }

    const int krl = lane >> 4;

    for (int s0 = c0; s0 < c0 + CHUNK; s0 += 64) {
        __syncthreads();
        for (int i = 0; i < 4; i++) {
            int ik = wave * 4 + i;
            int kr = ik * 4 + krl;
            int kc8 = (lane & 15) ^ (kr & 15);
            async16(k + (b * 2048 + s0 + kr) * 128 + kc8 * 8, &ks[ik * 512]);
        }
        __syncthreads();

        for (int ct = 0; ct < 4; ct++) {
            f32x4 Sf[2];
            Sf[0] = (f32x4){0.f,0.f,0.f,0.f};
            Sf[1] = (f32x4){0.f,0.f,0.f,0.f};
            int R = ct * 16 + l16;
            for (int c = 0; c < 4; c++) {
                int cc = c * 4 + quad;
                bf16x8 kb = *(const bf16x8*)&ks[(R * 16 + (cc ^ l16)) * 8];
                for (int m = 0; m < 2; m++)
                    Sf[m] = __builtin_amdgcn_mfma_f32_16x16x32_bf16(
                        qf[m][c], kb, Sf[m], 0, 0, 0);
            }
            float cs = 0.f;
            for (int m = 0; m < 2; m++)
                for (int r = 0; r < 4; r++)
                    cs += __expf(Sf[m][r] - 10.0f) * linv[m][r];
            cs += __shfl_xor(cs, 16);
            cs += __shfl_xor(cs, 32);
            if (quad == 0) wl[wave][(s0 - c0) + ct * 16 + l16] = cs;
        }
    }

    __syncthreads();
    {
        float s = wl[0][tid] + wl[1][tid] + wl[2][tid] + wl[3][tid];
        atomicAdd(&w[b * 2048 + c0 + tid], s);
    }
}

// ---------------------------------------------------------------------------
// Kernel 4 (wv): accum[b][d] = sum_k w[b][k] * V[k][d]  (V given as vt[b][d][k])
// grid (8 batches, 8 d-groups), 256 threads: 16 d x 16 s-ranges.
// ---------------------------------------------------------------------------
__global__ void wv(const float* __restrict__ w, const short* __restrict__ vt,
                   float* __restrict__ accum)
{
    const int b  = blockIdx.x;
    const int dg = blockIdx.y;
    const int tid = threadIdx.x;
    const int d  = dg * 16 + (tid >> 4);
    const int sr = (tid & 15) * 128;
    const float* wb = w + b * 2048 + sr;
    const short* vp = vt + (size_t)(b * 128 + d) * 2048 + sr;
    float s = 0.f;
    for (int i = 0; i < 128; i += 8) {
        bf16x8 v8 = *(const bf16x8*)(vp + i);
        for (int j = 0; j < 8; j++) s += wb[i + j] * bf2f(v8[j]);
    }
    s += __shfl_xor(s, 1);
    s += __shfl_xor(s, 2);
    s += __shfl_xor(s, 4);
    s += __shfl_xor(s, 8);
    if ((tid & 15) == 0) accum[b * 128 + d] = s;
}

// ---------------------------------------------------------------------------
// Kernel 5: out[b][c] = (accum[b][:]/2048) . Wl[:,c] + bl[c], fp32 out.
// ---------------------------------------------------------------------------
__global__ void final_proj(const float* __restrict__ accum, const float* __restrict__ Wl,
                           const float* __restrict__ bl, float* __restrict__ out)
{
    int id = blockIdx.x * 256 + threadIdx.x;
    if (id >= NB * CC) return;
    int b = id / CC, c = id % CC;
    float s = 0.f;
    for (int d = 0; d < 128; d++)
        s += accum[b * 128 + d] * Wl[d * 1000 + c];
    out[id] = s * (1.0f / 2048.0f) + bl[c];
}

// ---------------------------------------------------------------------------
extern "C" void kernel_launch(void* const* d_in, const int* in_sizes, int n_in,
                              void* d_out, int out_size, void* d_ws, size_t ws_size,
                              hipStream_t stream) {
    const float* x  = (const float*)d_in[0];
    const float* Wq = (const float*)d_in[1];
    const float* bq = (const float*)d_in[2];
    const float* Wk = (const float*)d_in[3];
    const float* bk = (const float*)d_in[4];
    const float* Wv = (const float*)d_in[5];
    const float* bv = (const float*)d_in[6];
    const float* Wl = (const float*)d_in[7];
    const float* bl = (const float*)d_in[8];
    float* out = (float*)d_out;

    char* ws = (char*)d_ws;
    short* qo     = (short*)(ws);                 // 4 MiB
    short* ko     = (short*)(ws + 4194304);       // 4 MiB
    short* vto    = (short*)(ws + 8388608);       // 4 MiB, [b][d][s]
    short* xb     = (short*)(ws + 12582912);      // 16 MiB (prep+qkv only)
    short* Wt     = (short*)(ws + 29360128);      // 384 KiB
    float* l_part = (float*)(ws + 29753344);      // 512 KiB (KC*8*2048 fp32)
    float* wbuf   = (float*)(ws + 30277632);      // 64 KiB (8*2048 fp32)
    float* acc    = (float*)(ws + 30343168);      // 4 KiB
    // total ~29 MiB of d_ws

    hipMemsetAsync(wbuf, 0, (size_t)NB * SS * sizeof(float), stream);
    prep<<<4864, 256, 0, stream>>>(x, Wq, Wk, Wv, xb, Wt);
    qkv_proj<<<dim3(128, 3), 256, 0, stream>>>(xb, Wt, bq, bk, bv, qo, ko, vto);
    attn_l<<<dim3(16, 8, KC), 256, 0, stream>>>(qo, ko, l_part);
    attn_w<<<dim3(16, 8, KC), 256, 0, stream>>>(qo, ko, l_part, wbuf);
    wv<<<dim3(8, 8), 256, 0, stream>>>(wbuf, vto, acc);
    final_proj<<<(NB * CC + 255) / 256, 256, 0, stream>>>(acc, Wl, bl, out);
}

// Round 12
// 152.803 us; speedup vs baseline: 1.3899x; 1.0520x over previous
//
#include <hip/hip_runtime.h>
#include <stdint.h>

// B=8, S=2048, F=512, D=128, C=1000. I/O fp32; internal bf16 MFMA, fp32 accum.
// mean-attention restructure: w[k] = sum_s exp(S[s,k]-10)/l[s];
// sum_s attn_out = w . V  (V consumed row-major -> no transpose scatter).
// LDS tiles = XOR-swizzled 16B chunks: chunk (r,c) at r*C + (c ^ (r & (C-1))).
#define NB 8
#define SS 2048
#define FF 512
#define DD 128
#define CC 1000
#define KC 8              // KV split factor
#define CHUNK (SS / KC)   // 256

typedef __attribute__((ext_vector_type(8))) short bf16x8;
typedef __attribute__((ext_vector_type(4))) float f32x4;

__device__ __forceinline__ short f2bf(float f) {
    uint32_t u;
    __builtin_memcpy(&u, &f, 4);
    u = (u + 0x7fffu + ((u >> 16) & 1u)) >> 16;   // RNE
    return (short)u;
}
__device__ __forceinline__ float bf2f(short h) {
    uint32_t u = ((uint32_t)(uint16_t)h) << 16;
    float f;
    __builtin_memcpy(&f, &u, 4);
    return f;
}
// async 16B global->LDS; LDS dest = wave-uniform base + lane*16
__device__ __forceinline__ void async16(const void* g, void* l) {
    __builtin_amdgcn_global_load_lds(
        (const __attribute__((address_space(1))) uint32_t*)g,
        (__attribute__((address_space(3))) uint32_t*)l, 16, 0, 0);
}

// ---------------------------------------------------------------------------
// Kernel 0 (prep): cast x fp32->bf16 (blocks 0..4095) and transpose+cast the
// projection weights [F][D]f32 -> [D][F]bf16 (blocks 4096..4863).
// ---------------------------------------------------------------------------
__global__ void prep(const float* __restrict__ x,
                     const float* __restrict__ Wq, const float* __restrict__ Wk,
                     const float* __restrict__ Wv,
                     short* __restrict__ xb, short* __restrict__ Wt)
{
    int bx = blockIdx.x;
    if (bx < 4096) {
        int id = bx * 256 + threadIdx.x;
        const float4* src = (const float4*)x + id * 2;
        float4 a = src[0], b2 = src[1];
        bf16x8 o;
        o[0] = f2bf(a.x);  o[1] = f2bf(a.y);  o[2] = f2bf(a.z);  o[3] = f2bf(a.w);
        o[4] = f2bf(b2.x); o[5] = f2bf(b2.y); o[6] = f2bf(b2.z); o[7] = f2bf(b2.w);
        *(bf16x8*)(xb + id * 8) = o;
    } else {
        int id = (bx - 4096) * 256 + threadIdx.x;
        int w = id >> 16, rem = id & 65535;
        int n = rem >> 9, kx = rem & 511;
        const float* Wsrc = (w == 0) ? Wq : (w == 1) ? Wk : Wv;
        Wt[w * 65536 + n * 512 + kx] = f2bf(Wsrc[kx * 128 + n]);
    }
}

// ---------------------------------------------------------------------------
// Kernel 1: fused QKV projection via swizzled global_load_lds.
// C[16384x128] = xb[16384x512] @ Wt^T + bias. grid (128 m-tiles, 3 mats).
// ALL outputs row-major [s][d] -> identical coalesced epilogue (no V scatter).
// ---------------------------------------------------------------------------
__global__ __launch_bounds__(256) void qkv_proj(
    const short* __restrict__ xb, const short* __restrict__ Wt,
    const float* __restrict__ bq, const float* __restrict__ bk, const float* __restrict__ bv,
    short* __restrict__ qo, short* __restrict__ ko, short* __restrict__ vo)
{
    __shared__ __align__(16) short As[128 * 64];   // swizzled chunks, C=8
    __shared__ __align__(16) short Bs[128 * 64];

    const int m0   = blockIdx.x * 128;
    const int mat  = blockIdx.y;
    const int tid  = threadIdx.x;
    const int wave = tid >> 6, lane = tid & 63;
    const int quad = lane >> 4, l16 = lane & 15;
    const int wr = wave >> 1, wc = wave & 1;

    const short* Wm = Wt + mat * 65536;

    f32x4 acc[4][4];
    for (int i = 0; i < 4; i++)
        for (int j = 0; j < 4; j++) acc[i][j] = (f32x4){0.f, 0.f, 0.f, 0.f};

    const int sr = lane >> 3;
    const int sc = (lane & 7) ^ (sr & 7);

    for (int kk = 0; kk < 512; kk += 64) {
        __syncthreads();                           // prior iter frag reads done
        for (int i = 0; i < 4; i++) {
            int ins = wave * 4 + i;                // 0..15
            int r = ins * 8 + sr;
            async16(xb + (m0 + r) * 512 + kk + sc * 8, &As[ins * 512]);
            async16(Wm + r * 512 + kk + sc * 8,        &Bs[ins * 512]);
        }
        __syncthreads();                           // vmcnt drained -> visible

        for (int kc = 0; kc < 2; kc++) {
            bf16x8 af[4], bfr[4];
            for (int mt = 0; mt < 4; mt++) {
                int R = wr * 64 + mt * 16 + l16, cc = kc * 4 + quad;
                af[mt] = *(const bf16x8*)&As[(R * 8 + (cc ^ (R & 7))) * 8];
            }
            for (int nt = 0; nt < 4; nt++) {
                int R = wc * 64 + nt * 16 + l16, cc = kc * 4 + quad;
                bfr[nt] = *(const bf16x8*)&Bs[(R * 8 + (cc ^ (R & 7))) * 8];
            }
            for (int mt = 0; mt < 4; mt++)
                for (int nt = 0; nt < 4; nt++)
                    acc[mt][nt] = __builtin_amdgcn_mfma_f32_16x16x32_bf16(
                        af[mt], bfr[nt], acc[mt][nt], 0, 0, 0);
        }
    }

    const float* bias = (mat == 0) ? bq : (mat == 1) ? bk : bv;
    short* outp = (mat == 0) ? qo : (mat == 1) ? ko : vo;
    for (int mt = 0; mt < 4; mt++) {
        int grow_base = m0 + wr * 64 + mt * 16 + quad * 4;   // C/D row = quad*4+reg
        for (int nt = 0; nt < 4; nt++) {
            int col = wc * 64 + nt * 16 + l16;               // C/D col = lane&15
            float bb = bias[col];
            for (int r = 0; r < 4; r++)
                outp[(grow_base + r) * 128 + col] = f2bf(acc[mt][nt][r] + bb);
        }
    }
}

// ---------------------------------------------------------------------------
// Kernel 2 (pass 1): l_part[kc][b][row] = sum over this KV chunk of
// exp(q_row . k_s - 10).  128 q-rows/block (4 waves x 2 m-frags), KV tile 64.
// Block (0,0,0) also zero-inits accum (saves a memset dispatch).
// grid = (16 q-tiles, 8 batches, KC) = 1024 blocks.
// ---------------------------------------------------------------------------
__global__ __launch_bounds__(256) void attn_l(
    const short* __restrict__ q, const short* __restrict__ k,
    float* __restrict__ l_part, float* __restrict__ accum)
{
    __shared__ __align__(16) short ks[64 * 128];      // swizzled, C=16

    const int b  = blockIdx.y;
    const int q0 = blockIdx.x * 128;
    const int lq = blockIdx.z;
    const int c0 = lq * CHUNK;
    const int tid  = threadIdx.x;
    const int wave = tid >> 6, lane = tid & 63;
    const int quad = lane >> 4, l16 = lane & 15;

    if (blockIdx.x == 0 && blockIdx.y == 0 && blockIdx.z == 0) {
        accum[tid] = 0.f; accum[256 + tid] = 0.f;
        accum[512 + tid] = 0.f; accum[768 + tid] = 0.f;
    }

    bf16x8 qf[2][4];
    for (int m = 0; m < 2; m++)
        for (int c = 0; c < 4; c++)
            qf[m][c] = *(const bf16x8*)(q + (b * 2048 + q0 + wave * 32 + m * 16 + l16) * 128
                                          + c * 32 + quad * 8);

    float lsum[2][4] = {{0.f,0.f,0.f,0.f},{0.f,0.f,0.f,0.f}};
    const int krl = lane >> 4;                        // 0..3

    for (int s0 = c0; s0 < c0 + CHUNK; s0 += 64) {
        __syncthreads();
        for (int i = 0; i < 4; i++) {
            int ik = wave * 4 + i;                    // 0..15
            int kr = ik * 4 + krl;                    // 0..63
            int kc8 = (lane & 15) ^ (kr & 15);
            async16(k + (b * 2048 + s0 + kr) * 128 + kc8 * 8, &ks[ik * 512]);
        }
        __syncthreads();

        for (int ct = 0; ct < 4; ct++) {
            f32x4 Sf[2];
            Sf[0] = (f32x4){0.f,0.f,0.f,0.f};
            Sf[1] = (f32x4){0.f,0.f,0.f,0.f};
            int R = ct * 16 + l16;                    // R&15 == l16
            for (int c = 0; c < 4; c++) {
                int cc = c * 4 + quad;
                bf16x8 kb = *(const bf16x8*)&ks[(R * 16 + (cc ^ l16)) * 8];
                for (int m = 0; m < 2; m++)
                    Sf[m] = __builtin_amdgcn_mfma_f32_16x16x32_bf16(
                        qf[m][c], kb, Sf[m], 0, 0, 0);
            }
            for (int m = 0; m < 2; m++)
                for (int r = 0; r < 4; r++)
                    lsum[m][r] += __expf(Sf[m][r] - 10.0f);
        }
    }

    for (int m = 0; m < 2; m++)
        for (int r = 0; r < 4; r++) {
            float lv = lsum[m][r];
            lv += __shfl_xor(lv, 1);
            lv += __shfl_xor(lv, 2);
            lv += __shfl_xor(lv, 4);
            lv += __shfl_xor(lv, 8);
            if (l16 == 0)
                l_part[(lq * 8 + b) * 2048 + q0 + wave * 32 + m * 16 + quad * 4 + r] = lv;
        }
}

// ---------------------------------------------------------------------------
// Kernel 3 (pass 2): w_part[qt][b][k] = sum over this block's 128 q-rows of
// exp(S-10)/l_total[row].  Plain stores (unique per block) -> no atomics,
// no zero-init.  grid = (16, 8, KC).
// ---------------------------------------------------------------------------
__global__ __launch_bounds__(256) void attn_w(
    const short* __restrict__ q, const short* __restrict__ k,
    const float* __restrict__ l_part, float* __restrict__ w_part)
{
    __shared__ __align__(16) short ks[64 * 128];      // swizzled, C=16
    __shared__ float wl[4][256];

    const int b  = blockIdx.y;
    const int qt = blockIdx.x;
    const int q0 = qt * 128;
    const int lq = blockIdx.z;
    const int c0 = lq * CHUNK;
    const int tid  = threadIdx.x;
    const int wave = tid >> 6, lane = tid & 63;
    const int quad = lane >> 4, l16 = lane & 15;

    bf16x8 qf[2][4];
    for (int m = 0; m < 2; m++)
        for (int c = 0; c < 4; c++)
            qf[m][c] = *(const bf16x8*)(q + (b * 2048 + q0 + wave * 32 + m * 16 + l16) * 128
                                          + c * 32 + quad * 8);

    float linv[2][4];
    for (int m = 0; m < 2; m++)
        for (int r = 0; r < 4; r++) {
            int row = q0 + wave * 32 + m * 16 + quad * 4 + r;
            float lt = 0.f;
            for (int kc = 0; kc < KC; kc++) lt += l_part[(kc * 8 + b) * 2048 + row];
            linv[m][r] = 1.0f / lt;
        }

    const int krl = lane >> 4;

    for (int s0 = c0; s0 < c0 + CHUNK; s0 += 64) {
        __syncthreads();
        for (int i = 0; i < 4; i++) {
            int ik = wave * 4 + i;
            int kr = ik * 4 + krl;
            int kc8 = (lane & 15) ^ (kr & 15);
            async16(k + (b * 2048 + s0 + kr) * 128 + kc8 * 8, &ks[ik * 512]);
        }
        __syncthreads();

        for (int ct = 0; ct < 4; ct++) {
            f32x4 Sf[2];
            Sf[0] = (f32x4){0.f,0.f,0.f,0.f};
            Sf[1] = (f32x4){0.f,0.f,0.f,0.f};
            int R = ct * 16 + l16;
            for (int c = 0; c < 4; c++) {
                int cc = c * 4 + quad;
                bf16x8 kb = *(const bf16x8*)&ks[(R * 16 + (cc ^ l16)) * 8];
                for (int m = 0; m < 2; m++)
                    Sf[m] = __builtin_amdgcn_mfma_f32_16x16x32_bf16(
                        qf[m][c], kb, Sf[m], 0, 0, 0);
            }
            float cs = 0.f;
            for (int m = 0; m < 2; m++)
                for (int r = 0; r < 4; r++)
                    cs += __expf(Sf[m][r] - 10.0f) * linv[m][r];
            cs += __shfl_xor(cs, 16);
            cs += __shfl_xor(cs, 32);
            if (quad == 0) wl[wave][(s0 - c0) + ct * 16 + l16] = cs;
        }
    }

    __syncthreads();
    {
        float s = wl[0][tid] + wl[1][tid] + wl[2][tid] + wl[3][tid];
        w_part[(qt * 8 + b) * 2048 + c0 + tid] = s;
    }
}

// ---------------------------------------------------------------------------
// Kernel 4 (wv): accum[b][d] += sum_s w[b][s] * V[b][s][d], V row-major.
// w[b][s] = sum_qt w_part[qt][b][s], staged per-slab in LDS.
// grid (8 batches, 8 s-slabs of 256), 256 threads (128 d x 2 halves).
// ---------------------------------------------------------------------------
__global__ void wv(const float* __restrict__ w_part, const short* __restrict__ vo,
                   float* __restrict__ accum)
{
    __shared__ float wsh[256];
    const int b    = blockIdx.x;
    const int slab = blockIdx.y;
    const int tid  = threadIdx.x;

    int s = slab * 256 + tid;
    float wsum = 0.f;
    for (int qt = 0; qt < 16; qt++) wsum += w_part[(qt * 8 + b) * 2048 + s];
    wsh[tid] = wsum;
    __syncthreads();

    const int d = tid & 127, h = tid >> 7;
    float a = 0.f;
    for (int i = 0; i < 128; i++) {
        int sl = h * 128 + i;
        a += wsh[sl] * bf2f(vo[(size_t)(b * 2048 + slab * 256 + sl) * 128 + d]);
    }
    atomicAdd(&accum[b * 128 + d], a);
}

// ---------------------------------------------------------------------------
// Kernel 5: out[b][c] = (accum[b][:]/2048) . Wl[:,c] + bl[c], fp32 out.
// ---------------------------------------------------------------------------
__global__ void final_proj(const float* __restrict__ accum, const float* __restrict__ Wl,
                           const float* __restrict__ bl, float* __restrict__ out)
{
    int id = blockIdx.x * 256 + threadIdx.x;
    if (id >= NB * CC) return;
    int b = id / CC, c = id % CC;
    float s = 0.f;
    for (int d = 0; d < 128; d++)
        s += accum[b * 128 + d] * Wl[d * 1000 + c];
    out[id] = s * (1.0f / 2048.0f) + bl[c];
}

// ---------------------------------------------------------------------------
extern "C" void kernel_launch(void* const* d_in, const int* in_sizes, int n_in,
                              void* d_out, int out_size, void* d_ws, size_t ws_size,
                              hipStream_t stream) {
    const float* x  = (const float*)d_in[0];
    const float* Wq = (const float*)d_in[1];
    const float* bq = (const float*)d_in[2];
    const float* Wk = (const float*)d_in[3];
    const float* bk = (const float*)d_in[4];
    const float* Wv = (const float*)d_in[5];
    const float* bv = (const float*)d_in[6];
    const float* Wl = (const float*)d_in[7];
    const float* bl = (const float*)d_in[8];
    float* out = (float*)d_out;

    char* ws = (char*)d_ws;
    short* qo     = (short*)(ws);                 // 4 MiB
    short* ko     = (short*)(ws + 4194304);       // 4 MiB
    short* vo     = (short*)(ws + 8388608);       // 4 MiB, row-major [b][s][d]
    short* xb     = (short*)(ws + 12582912);      // 16 MiB (prep+qkv only)
    short* Wt     = (short*)(ws + 29360128);      // 384 KiB
    float* l_part = (float*)(ws + 29753344);      // 512 KiB (KC*8*2048 fp32)
    float* w_part = (float*)(ws + 30277632);      // 1 MiB (16*8*2048 fp32)
    float* acc    = (float*)(ws + 31326208);      // 4 KiB
    // total ~30 MiB of d_ws

    prep<<<4864, 256, 0, stream>>>(x, Wq, Wk, Wv, xb, Wt);
    qkv_proj<<<dim3(128, 3), 256, 0, stream>>>(xb, Wt, bq, bk, bv, qo, ko, vo);
    attn_l<<<dim3(16, 8, KC), 256, 0, stream>>>(qo, ko, l_part, acc);
    attn_w<<<dim3(16, 8, KC), 256, 0, stream>>>(qo, ko, l_part, w_part);
    wv<<<dim3(8, 8), 256, 0, stream>>>(w_part, vo, acc);
    final_proj<<<(NB * CC + 255) / 256, 256, 0, stream>>>(acc, Wl, bl, out);
}